// Round 6
// baseline (708.739 us; speedup 1.0000x reference)
//
#include <hip/hip_runtime.h>

#define NB 256
#define NT 4096

typedef unsigned int u32;
typedef unsigned long long u64;
typedef int v2i __attribute__((ext_vector_type(2)));

template <int CTRL>
__device__ __forceinline__ float dppf(float x) {
  return __int_as_float(__builtin_amdgcn_update_dpp(
      0, __float_as_int(x), CTRL, 0xF, 0xF, true));
}

// max with lane^16 partner
__device__ __forceinline__ float pl16max(float x) {
#if __has_builtin(__builtin_amdgcn_permlane16_swap)
  v2i r = __builtin_amdgcn_permlane16_swap(__float_as_int(x), __float_as_int(x),
                                           false, false);
  return fmaxf(__int_as_float(r[0]), __int_as_float(r[1]));
#else
  return fmaxf(x, __shfl_xor(x, 16, 64));
#endif
}

// max with lane^32 partner
__device__ __forceinline__ float pl32max(float x) {
#if __has_builtin(__builtin_amdgcn_permlane32_swap)
  v2i r = __builtin_amdgcn_permlane32_swap(__float_as_int(x), __float_as_int(x),
                                           false, false);
  return fmaxf(__int_as_float(r[0]), __int_as_float(r[1]));
#else
  return fmaxf(x, __shfl_xor(x, 32, 64));
#endif
}

__global__ void __launch_bounds__(64, 1)
viterbi_k(const float* __restrict__ feats, const float* __restrict__ trans,
          float* __restrict__ out) {
  // LDS: psi + path only = 20 KB (no staging buffers anymore)
  __shared__ u32 s_psi[NT];
  __shared__ u32 s_path[NT / 4];

  const int b = blockIdx.x;
  const int lane = (int)threadIdx.x;
  const int g = lane >> 3;        // group index
  const int l = lane & 7;         // in-group index
  const bool lhi = (l >= 6);
  const bool ghi = (g >= 6);
  const int gg = (g < 6) ? g : 5;
  const int jj = lhi ? 5 : l;
  // A-step (odd t): roles i=g, j=l; B-step (even t): roles i=l, j=g
  const int offTA = gg * 6 + jj;   // word offset for trans[t][i=g][j=l]
  const int offTB = jj * 6 + gg;   // word offset for trans[t][i=l][j=g]
  const int offFA = gg;            // feat[t][i=g]
  const int offFB = jj;            // feat[t][i=l]
  const float ninf = __int_as_float(0xff800000u);

  const float* trb = trans + (size_t)b * NT * 36;
  const float* ftb = feats + (size_t)b * NT * 6;

  // layout0: lane (g,l) holds delta[l]
  float delta = (l == 4) ? 0.0f : ((l < 6) ? -10000.0f : ninf);
  u32 mlo = 0, mhi = 0;

  // consumes layout0, produces layout1 (lane (g,l) -> delta_new[g])
  auto stepA = [&](float tr, float ft, int slot) {
    float s = tr + delta;                   // exact: same single add as ref
    float m = fmaxf(s, dppf<0xB1>(s));      // xor1 (quad_perm 1,0,3,2)
    m = fmaxf(m, dppf<0x4E>(m));            // xor2 (quad_perm 2,3,0,1)
    m = fmaxf(m, dppf<0x141>(m));           // xor4 via row_half_mirror (1 op)
    u64 bal = __ballot(s == m);             // bits at 8i+j
    bool cap = (lane == slot);
    mlo = cap ? (u32)bal : mlo;
    mhi = cap ? (u32)(bal >> 32) : mhi;
    delta = m + ft;
  };

  // consumes layout1, produces layout0 (lane (g,l) -> delta_new[l])
  auto stepB = [&](float tr, float ft, int slot) {
    float s = tr + delta;
    float m = fmaxf(s, dppf<0x128>(s));     // xor8 (row_ror:8)
    m = pl16max(m);                         // xor16
    m = pl32max(m);                         // xor32
    u64 bal = __ballot(s == m);             // bits at 8j+i
    bool cap = (lane == slot);
    mlo = cap ? (u32)bal : mlo;
    mhi = cap ? (u32)(bal >> 32) : mhi;
    delta = m + ft;
  };

  auto flush = [&](int base) {  // lane holds ballot of step base+lane
    const u32 ub = (u32)(base >> 6) & 63;
    // A-unpack (odd step => odd lane): psi_i = ctz of (bal >> 8i) & 63
    u32 pA = (u32)__builtin_ctz((mlo & 63u) | 64u);
    pA |= (u32)__builtin_ctz(((mlo >> 8) & 63u) | 64u) << 3;
    pA |= (u32)__builtin_ctz(((mlo >> 16) & 63u) | 64u) << 6;
    pA |= (u32)__builtin_ctz(((mlo >> 24) & 63u) | 64u) << 9;
    pA |= (u32)__builtin_ctz((mhi & 63u) | 64u) << 12;
    pA |= (u32)__builtin_ctz(((mhi >> 8) & 63u) | 64u) << 15;
    // B-unpack (even step => even lane): bits for state i at 8j+i
    u64 bal = ((u64)mhi << 32) | (u64)mlo;
    u32 pB = 0;
#pragma unroll
    for (int i = 0; i < 6; ++i) {
      u64 mm = (bal >> i) & 0x0000010101010101ULL;
      u32 j = (u32)(__builtin_ctzll(mm | (1ULL << 48)) >> 3);
      pB |= j << (3 * i);
    }
    u32 p = (lane & 1) ? pA : pB;
    s_psi[base + (((u32)lane) ^ ub)] = p;   // bank-swizzled slot
  };

// Load one 8-step group (tr, ft) straight from global into registers.
// Scalar base per group + per-lane constant voffset + imm offsets.
#define LOADG(TRV, FTV, GID)                                                  \
  {                                                                           \
    int g8 = (GID) * 8;                                                       \
    if (g8 > NT - 8) g8 = NT - 8; /* clamp prefetch past end (last batch) */  \
    const float* trg = trb + (size_t)g8 * 36;                                 \
    const float* ftg = ftb + (size_t)g8 * 6;                                  \
    _Pragma("unroll") for (int q = 0; q < 8; ++q) {                           \
      TRV[q] = trg[q * 36 + ((q & 1) ? offTA : offTB)];                       \
      FTV[q] = ftg[q * 6 + ((q & 1) ? offFA : offFB)];                        \
    }                                                                         \
  }

#define STEPS8(TRV, FTV, B8)                                                  \
  {                                                                           \
    _Pragma("unroll") for (int q = 0; q < 8; ++q) {                           \
      if (q & 1) stepA(lhi ? ninf : TRV[q], FTV[q], (B8) + q);                \
      else       stepB(ghi ? ninf : TRV[q], FTV[q], (B8) + q);                \
    }                                                                         \
  }

  float tr0[8], ft0[8], tr1[8], ft1[8], tr2[8], ft2[8], tr3[8], ft3[8];
  LOADG(tr0, ft0, 0)
  LOADG(tr1, ft1, 1)
  LOADG(tr2, ft2, 2)
  LOADG(tr3, ft3, 3)

  // 64 windows of 64 steps; 8 groups/window; buffers rotate mod 4
#pragma unroll 1
  for (int w = 0; w < NT / 64; ++w) {
    const int gbase = w * 8;
    if (w == 0) {  // skip t=0 (init delta carries no feat/trans)
#pragma unroll
      for (int q = 1; q < 8; ++q) {
        if (q & 1) stepA(lhi ? ninf : tr0[q], ft0[q], q);
        else       stepB(ghi ? ninf : tr0[q], ft0[q], q);
      }
    } else {
      STEPS8(tr0, ft0, 0)
    }
    LOADG(tr0, ft0, gbase + 4)
    STEPS8(tr1, ft1, 8)
    LOADG(tr1, ft1, gbase + 5)
    STEPS8(tr2, ft2, 16)
    LOADG(tr2, ft2, gbase + 6)
    STEPS8(tr3, ft3, 24)
    LOADG(tr3, ft3, gbase + 7)
    STEPS8(tr0, ft0, 32)
    LOADG(tr0, ft0, gbase + 8)
    STEPS8(tr1, ft1, 40)
    LOADG(tr1, ft1, gbase + 9)
    STEPS8(tr2, ft2, 48)
    LOADG(tr2, ft2, gbase + 10)
    STEPS8(tr3, ft3, 56)
    LOADG(tr3, ft3, gbase + 11)
    flush(w * 64);
  }

  // ---- score + last_tag. Final step t=4095 is stepA -> layout1:
  // lane (g,l) holds delta_final[g]; groups 6,7 duplicate state 5 exactly.
  float sm = delta;
  sm = fmaxf(sm, dppf<0xB1>(sm));
  sm = fmaxf(sm, dppf<0x4E>(sm));
  sm = fmaxf(sm, dppf<0x141>(sm));
  sm = fmaxf(sm, dppf<0x128>(sm));
  sm = pl16max(sm);
  sm = pl32max(sm);
  u64 bs = __ballot(delta == sm);
  int last_tag = (int)((__builtin_ctzll(bs) >> 3) & 7);  // smallest g wins ties

  __syncthreads();  // all psi visible

  // ---- per-segment backpointer-map composition (exact integer scan)
  const int u = lane;
  u32 Gm = 0u | (1u << 3) | (2u << 6) | (3u << 9) | (4u << 12) | (5u << 15);
#pragma unroll 1
  for (int k = 0; k < 64; ++k) {
    u32 p = s_psi[u * 64 + (k ^ u)];
    u32 ng = 0;
#pragma unroll
    for (int x = 0; x < 6; ++x) {
      u32 j = (p >> (3 * x)) & 7;
      u32 v = (Gm >> (3 * ((j < 6) ? j : 0))) & 7;  // clamp garbage fields
      ng |= v << (3 * x);
    }
    Gm = ng;
  }

  // ---- boundary-tag chain via readlane (uniform, register-only)
  int bcur = last_tag;
  int my_b = last_tag;  // lane 63
#pragma unroll 1
  for (int v = 63; v >= 1; --v) {
    u32 Gv = (u32)__builtin_amdgcn_readlane((int)Gm, v);
    bcur = (int)((Gv >> (3 * bcur)) & 7);
    my_b = (u == v - 1) ? bcur : my_b;
  }

  // ---- per-segment walk, emit path bytes
  {
    int tag = my_b;
    unsigned char* pb = (unsigned char*)s_path;
    pb[u * 64 + 63] = (unsigned char)tag;
#pragma unroll 1
    for (int k = 63; k >= 1; --k) {
      u32 p = s_psi[u * 64 + (k ^ u)];
      tag = (int)((p >> (3 * tag)) & 7);
      pb[u * 64 + k - 1] = (unsigned char)tag;
    }
  }
  if (lane == 0) out[b] = sm;
  __syncthreads();

  // ---- coalesced float path store
  float* outp = out + NB + (size_t)b * NT;
#pragma unroll
  for (int i = 0; i < (NT / 4) / 64; ++i) {
    u32 w = s_path[lane + i * 64];
    float4 f;
    f.x = (float)(w & 255u);
    f.y = (float)((w >> 8) & 255u);
    f.z = (float)((w >> 16) & 255u);
    f.w = (float)((w >> 24) & 255u);
    ((float4*)outp)[lane + i * 64] = f;
  }
}

extern "C" void kernel_launch(void* const* d_in, const int* in_sizes, int n_in,
                              void* d_out, int out_size, void* d_ws, size_t ws_size,
                              hipStream_t stream) {
  (void)in_sizes; (void)n_in; (void)out_size; (void)d_ws; (void)ws_size;
  const float* feats = (const float*)d_in[0];
  const float* trans = (const float*)d_in[1];
  float* out = (float*)d_out;
  hipLaunchKernelGGL(viterbi_k, dim3(NB), dim3(64), 0, stream, feats, trans, out);
}

// Round 7
// 273.463 us; speedup vs baseline: 2.5917x; 2.5917x over previous
//
#include <hip/hip_runtime.h>

#define NB 256
#define NT 4096
#define CH 128
#define NCHUNK (NT / CH)

typedef unsigned int u32;
typedef unsigned long long u64;
typedef int v2i __attribute__((ext_vector_type(2)));

typedef __attribute__((address_space(1))) const u32 gas_u32;
typedef __attribute__((address_space(3))) u32 las_u32;

__device__ __forceinline__ void gll16(const void* g, void* l) {
  __builtin_amdgcn_global_load_lds((gas_u32*)g, (las_u32*)l, 16, 0, 0);
}

template <int CTRL>
__device__ __forceinline__ float dppf(float x) {
  return __int_as_float(__builtin_amdgcn_update_dpp(
      0, __float_as_int(x), CTRL, 0xF, 0xF, true));
}

__device__ __forceinline__ float max3f(float a, float b, float c) {
  return fmaxf(fmaxf(a, b), c);   // fuses to v_max3_f32
}

// pair-set {x[l], x[l^16]} across the two outputs
__device__ __forceinline__ v2i pl16pair(float x) {
#if __has_builtin(__builtin_amdgcn_permlane16_swap)
  return __builtin_amdgcn_permlane16_swap(__float_as_int(x), __float_as_int(x),
                                          false, false);
#else
  v2i r; r[0] = __float_as_int(x); r[1] = __float_as_int(__shfl_xor(x, 16, 64));
  return r;
#endif
}

// pair-set {x[l], x[l^32]}
__device__ __forceinline__ v2i pl32pair(float x) {
#if __has_builtin(__builtin_amdgcn_permlane32_swap)
  return __builtin_amdgcn_permlane32_swap(__float_as_int(x), __float_as_int(x),
                                          false, false);
#else
  v2i r; r[0] = __float_as_int(x); r[1] = __float_as_int(__shfl_xor(x, 32, 64));
  return r;
#endif
}

__device__ __forceinline__ float pl16max(float x) {
  v2i r = pl16pair(x);
  return fmaxf(__int_as_float(r[0]), __int_as_float(r[1]));
}
__device__ __forceinline__ float pl32max(float x) {
  v2i r = pl32pair(x);
  return fmaxf(__int_as_float(r[0]), __int_as_float(r[1]));
}

__global__ void __launch_bounds__(64, 1)
viterbi_k(const float* __restrict__ feats, const float* __restrict__ trans,
          float* __restrict__ out) {
  // LDS: 36864 + 6144 + 16384 + 4096 = 63488 B (< 64KB)
  __shared__ __align__(16) float s_tr[2 * CH * 36];
  __shared__ __align__(16) float s_ft[2 * CH * 6];
  __shared__ u32 s_psi[NT];
  __shared__ u32 s_path[NT / 4];

  const int b = blockIdx.x;
  const int lane = (int)threadIdx.x;
  const int g = lane >> 3;        // group index
  const int l = lane & 7;         // in-group index
  const bool lhi = (l >= 6);
  const bool ghi = (g >= 6);
  const int gg = (g < 6) ? g : 5;
  const int jj = lhi ? 5 : l;
  // A-step (odd t): roles i=g, j=l; B-step (even t): roles i=l, j=g
  const int offTA = gg * 6 + jj;   // trans[t][i=g][j=l]
  const int offTB = jj * 6 + gg;   // trans[t][i=l][j=g]
  const int offFA = gg;            // feat[t][i=g]
  const int offFB = jj;            // feat[t][i=l]
  const float ninf = __int_as_float(0xff800000u);

  const float* trb = trans + (size_t)b * NT * 36;
  const float* ftb = feats + (size_t)b * NT * 6;

  // layout0: lane (g,l) holds delta[l]
  float delta = (l == 4) ? 0.0f : ((l < 6) ? -10000.0f : ninf);
  u32 mlo = 0, mhi = 0;

  auto stage = [&](int c) {
    const int buf = c & 1;
    const float* gt = trb + (size_t)c * CH * 36;
    float* lt = s_tr + buf * (CH * 36);
#pragma unroll
    for (int i = 0; i < 18; ++i) gll16(gt + i * 256 + lane * 4, lt + i * 256);
    const float* gf = ftb + (size_t)c * CH * 6;
    float* lf = s_ft + buf * (CH * 6);
#pragma unroll
    for (int i = 0; i < 3; ++i) gll16(gf + i * 256 + lane * 4, lf + i * 256);
  };

  // consumes layout0, produces layout1 (lane (g,l) -> delta_new[g])
  // depth-minimal 8-way max within 8-lane group:
  // {s,v1,v2,v3} = s[l^{0,1,2,3}], h=mirror -> s[l^7], {h1,h2,h3}=s[l^{6,5,4}]
  auto stepA = [&](float tr, float ft, int slot) {
    float s = tr + delta;                   // exact: same single add as ref
    float v1 = dppf<0xB1>(s);               // quad xor1
    float v2 = dppf<0x4E>(s);               // quad xor2
    float v3 = dppf<0x1B>(s);               // quad reverse (xor3)
    float h  = dppf<0x141>(s);              // row_half_mirror (l -> 7-l)
    float h1 = dppf<0xB1>(h);
    float h2 = dppf<0x4E>(h);
    float h3 = dppf<0x1B>(h);
    float A = max3f(s, v1, v2);
    float B = max3f(v3, h, h1);
    float C = fmaxf(h2, h3);
    float m = max3f(A, B, C);
    u64 bal = __ballot(s == m);             // bits at 8i+j
    bool cap = (lane == slot);
    mlo = cap ? (u32)bal : mlo;
    mhi = cap ? (u32)(bal >> 32) : mhi;
    delta = m + ft;
  };

  // consumes layout1, produces layout0 (lane (g,l) -> delta_new[l])
  // stride-8 8-way max via pair-doubling (duplicates harmless under max):
  // c = {0,32}; p = pl16 of both -> {0,16,32,48}; ror8 of those -> {8,24,40,56}
  auto stepB = [&](float tr, float ft, int slot) {
    float s = tr + delta;
    v2i c = pl32pair(s);
    float c0 = __int_as_float(c[0]), c1 = __int_as_float(c[1]);
    v2i p0 = pl16pair(c0), p1 = pl16pair(c1);
    float p00 = __int_as_float(p0[0]), p01 = __int_as_float(p0[1]);
    float p10 = __int_as_float(p1[0]), p11 = __int_as_float(p1[1]);
    float r0 = dppf<0x128>(p00), r1 = dppf<0x128>(p01);
    float r2 = dppf<0x128>(p10), r3 = dppf<0x128>(p11);
    float T1 = max3f(p00, p01, p10);
    float T2 = max3f(p11, r0, r1);
    float T3 = fmaxf(r2, r3);
    float m = max3f(T1, T2, T3);
    u64 bal = __ballot(s == m);             // bits at 8j+i
    bool cap = (lane == slot);
    mlo = cap ? (u32)bal : mlo;
    mhi = cap ? (u32)(bal >> 32) : mhi;
    delta = m + ft;
  };

  auto flush = [&](int base) {  // lane holds ballot of step base+lane
    const u32 ub = (u32)(base >> 6) & 63;
    // A-unpack (odd step => odd lane): psi_i = ctz of (bal >> 8i) & 63
    u32 pA = (u32)__builtin_ctz((mlo & 63u) | 64u);
    pA |= (u32)__builtin_ctz(((mlo >> 8) & 63u) | 64u) << 3;
    pA |= (u32)__builtin_ctz(((mlo >> 16) & 63u) | 64u) << 6;
    pA |= (u32)__builtin_ctz(((mlo >> 24) & 63u) | 64u) << 9;
    pA |= (u32)__builtin_ctz((mhi & 63u) | 64u) << 12;
    pA |= (u32)__builtin_ctz(((mhi >> 8) & 63u) | 64u) << 15;
    // B-unpack (even step => even lane): bits for state i at 8j+i
    u64 bal = ((u64)mhi << 32) | (u64)mlo;
    u32 pB = 0;
#pragma unroll
    for (int i = 0; i < 6; ++i) {
      u64 mm = (bal >> i) & 0x0000010101010101ULL;
      u32 j = (u32)(__builtin_ctzll(mm | (1ULL << 48)) >> 3);
      pB |= j << (3 * i);
    }
    u32 p = (lane & 1) ? pA : pB;
    s_psi[base + (((u32)lane) ^ ub)] = p;   // bank-swizzled slot
  };

// group load: 8 steps' (tr, ft) into register arrays (static indices only)
#define LOAD8(trv, ftv, g8base)                                               \
  {                                                                           \
    _Pragma("unroll") for (int q = 0; q < 8; ++q) {                           \
      trv[q] = trp[((g8base) + q) * 36 + ((q & 1) ? offTA : offTB)];          \
      ftv[q] = ftp[((g8base) + q) * 6 + ((q & 1) ? offFA : offFB)];           \
    }                                                                         \
  }

#define STEPS8(trv, ftv, base)                                                \
  {                                                                           \
    _Pragma("unroll") for (int q = 0; q < 8; ++q) {                           \
      if (q & 1) stepA(lhi ? ninf : trv[q], ftv[q], ((base) + q) & 63);       \
      else       stepB(ghi ? ninf : trv[q], ftv[q], ((base) + q) & 63);       \
    }                                                                         \
  }

  stage(0);
  asm volatile("s_waitcnt vmcnt(0)" ::: "memory");
  stage(1);

  // ---- chunk 0 (t = 1..127; t=0 skipped). t odd -> stepA, t even -> stepB.
  {
    const float* trp = s_tr;
    const float* ftp = s_ft;
    float trA[8], ftA[8], trB[8], ftB[8];
    LOAD8(trA, ftA, 0);
    LOAD8(trB, ftB, 8);
    // steps 1..7 (skip t=0)
#pragma unroll
    for (int q = 1; q < 8; ++q) {
      if (q & 1) stepA(lhi ? ninf : trA[q], ftA[q], q);
      else       stepB(ghi ? ninf : trA[q], ftA[q], q);
    }
    LOAD8(trA, ftA, 16);
    STEPS8(trB, ftB, 8);
#pragma unroll 1
    for (int g2 = 2; g2 < 16; g2 += 2) {
      LOAD8(trB, ftB, (g2 + 1) * 8);
      STEPS8(trA, ftA, g2 * 8);
      LOAD8(trA, ftA, (g2 + 2) * 8);   // g2==14 -> in-LDS garbage, never consumed
      STEPS8(trB, ftB, (g2 + 1) * 8);
      if ((g2 & 7) == 6) flush((g2 & 8) * 8);
    }
  }

  // ---- chunks 1..31 (tbase even => t parity == q parity)
#pragma unroll 1
  for (int c = 1; c < NCHUNK; ++c) {
    asm volatile("s_waitcnt vmcnt(0)" ::: "memory");   // chunk c resident
    if (c + 1 < NCHUNK) stage(c + 1);
    const int buf = c & 1;
    const float* trp = s_tr + buf * (CH * 36);
    const float* ftp = s_ft + buf * (CH * 6);
    const int tbase = c * CH;
    float trA[8], ftA[8], trB[8], ftB[8];
    LOAD8(trA, ftA, 0);
#pragma unroll 1
    for (int g2 = 0; g2 < 16; g2 += 2) {
      LOAD8(trB, ftB, (g2 + 1) * 8);
      STEPS8(trA, ftA, tbase + g2 * 8);
      LOAD8(trA, ftA, (g2 + 2) * 8);   // g2==14 -> in-LDS garbage, never consumed
      STEPS8(trB, ftB, tbase + (g2 + 1) * 8);
      if ((g2 & 7) == 6) flush(tbase + (g2 & 8) * 8);
    }
  }

  // ---- score + last_tag. Final step t=4095 is stepA -> layout1:
  // lane (g,l) holds delta_final[g]; groups 6,7 duplicate state 5 exactly.
  float sm = delta;
  sm = fmaxf(sm, dppf<0xB1>(sm));
  sm = fmaxf(sm, dppf<0x4E>(sm));
  sm = fmaxf(sm, dppf<0x141>(sm));
  sm = fmaxf(sm, dppf<0x128>(sm));
  sm = pl16max(sm);
  sm = pl32max(sm);
  u64 bs = __ballot(delta == sm);
  int last_tag = (int)((__builtin_ctzll(bs) >> 3) & 7);  // smallest g wins ties

  __syncthreads();  // all psi visible

  // ---- per-segment backpointer-map composition (exact integer scan)
  const int u = lane;
  u32 Gm = 0u | (1u << 3) | (2u << 6) | (3u << 9) | (4u << 12) | (5u << 15);
#pragma unroll 1
  for (int k = 0; k < 64; ++k) {
    u32 p = s_psi[u * 64 + (k ^ u)];
    u32 ng = 0;
#pragma unroll
    for (int x = 0; x < 6; ++x) {
      u32 j = (p >> (3 * x)) & 7;
      u32 v = (Gm >> (3 * ((j < 6) ? j : 0))) & 7;  // clamp garbage fields
      ng |= v << (3 * x);
    }
    Gm = ng;
  }

  // ---- boundary-tag chain via readlane (uniform, register-only)
  int bcur = last_tag;
  int my_b = last_tag;  // lane 63
#pragma unroll 1
  for (int v = 63; v >= 1; --v) {
    u32 Gv = (u32)__builtin_amdgcn_readlane((int)Gm, v);
    bcur = (int)((Gv >> (3 * bcur)) & 7);
    my_b = (u == v - 1) ? bcur : my_b;
  }

  // ---- per-segment walk, emit path bytes
  {
    int tag = my_b;
    unsigned char* pb = (unsigned char*)s_path;
    pb[u * 64 + 63] = (unsigned char)tag;
#pragma unroll 1
    for (int k = 63; k >= 1; --k) {
      u32 p = s_psi[u * 64 + (k ^ u)];
      tag = (int)((p >> (3 * tag)) & 7);
      pb[u * 64 + k - 1] = (unsigned char)tag;
    }
  }
  if (lane == 0) out[b] = sm;
  __syncthreads();

  // ---- coalesced float path store
  float* outp = out + NB + (size_t)b * NT;
#pragma unroll
  for (int i = 0; i < (NT / 4) / 64; ++i) {
    u32 w = s_path[lane + i * 64];
    float4 f;
    f.x = (float)(w & 255u);
    f.y = (float)((w >> 8) & 255u);
    f.z = (float)((w >> 16) & 255u);
    f.w = (float)((w >> 24) & 255u);
    ((float4*)outp)[lane + i * 64] = f;
  }
}

extern "C" void kernel_launch(void* const* d_in, const int* in_sizes, int n_in,
                              void* d_out, int out_size, void* d_ws, size_t ws_size,
                              hipStream_t stream) {
  (void)in_sizes; (void)n_in; (void)out_size; (void)d_ws; (void)ws_size;
  const float* feats = (const float*)d_in[0];
  const float* trans = (const float*)d_in[1];
  float* out = (float*)d_out;
  hipLaunchKernelGGL(viterbi_k, dim3(NB), dim3(64), 0, stream, feats, trans, out);
}

// Round 8
// 242.190 us; speedup vs baseline: 2.9264x; 1.1291x over previous
//
#include <hip/hip_runtime.h>

#define NB 256
#define NT 4096
#define CH 128
#define NCHUNK (NT / CH)

typedef unsigned int u32;
typedef unsigned long long u64;
typedef int v2i __attribute__((ext_vector_type(2)));

typedef __attribute__((address_space(1))) const u32 gas_u32;
typedef __attribute__((address_space(3))) u32 las_u32;

__device__ __forceinline__ void gll16(const void* g, void* l) {
  __builtin_amdgcn_global_load_lds((gas_u32*)g, (las_u32*)l, 16, 0, 0);
}

template <int CTRL>
__device__ __forceinline__ float dppf(float x) {
  return __int_as_float(__builtin_amdgcn_update_dpp(
      0, __float_as_int(x), CTRL, 0xF, 0xF, true));
}

// max with lane^16 partner (cross-row), VALU-speed on gfx950
__device__ __forceinline__ float pl16max(float x) {
#if __has_builtin(__builtin_amdgcn_permlane16_swap)
  v2i r = __builtin_amdgcn_permlane16_swap(__float_as_int(x), __float_as_int(x),
                                           false, false);
  return fmaxf(__int_as_float(r[0]), __int_as_float(r[1]));
#else
  return fmaxf(x, __shfl_xor(x, 16, 64));
#endif
}

// max with lane^32 partner
__device__ __forceinline__ float pl32max(float x) {
#if __has_builtin(__builtin_amdgcn_permlane32_swap)
  v2i r = __builtin_amdgcn_permlane32_swap(__float_as_int(x), __float_as_int(x),
                                           false, false);
  return fmaxf(__int_as_float(r[0]), __int_as_float(r[1]));
#else
  return fmaxf(x, __shfl_xor(x, 32, 64));
#endif
}

__global__ void __launch_bounds__(64, 1)
viterbi_k(const float* __restrict__ feats, const float* __restrict__ trans,
          float* __restrict__ out) {
  // LDS: 36864 + 6144 + 16384 + 4096 = 63488 B (< 64KB)
  __shared__ __align__(16) float s_tr[2 * CH * 36];
  __shared__ __align__(16) float s_ft[2 * CH * 6];
  __shared__ u32 s_psi[NT];
  __shared__ u32 s_path[NT / 4];

  const int b = blockIdx.x;
  const int lane = (int)threadIdx.x;
  const int g = lane >> 3;        // group index
  const int l = lane & 7;         // in-group index
  const int gg = (g < 6) ? g : 5; // clamped -> duplicate-of-5 invariant
  const int jj = (l < 6) ? l : 5;
  // A-step (odd t): roles i=g, j=l; B-step (even t): roles i=l, j=g
  const int offTA = gg * 6 + jj;   // trans[t][i=g][j=l]
  const int offTB = jj * 6 + gg;   // trans[t][i=l][j=g]
  const int offFA = gg;            // feat[t][i=g]
  const int offFB = jj;            // feat[t][i=l]

  const float* trb = trans + (size_t)b * NT * 36;
  const float* ftb = feats + (size_t)b * NT * 6;

  // layout0: lane (g,l) holds delta[jj] — lanes l>=6 duplicate state 5.
  // Duplicates are harmless: max unaffected; psi unpack reads only bit
  // positions with i,j in 0..5; ctz tie-break: j=5's bit is set whenever a
  // duplicate (j=6,7) bit is, so the smallest true index always wins.
  float delta = (l == 4) ? 0.0f : -10000.0f;
  u32 mlo = 0, mhi = 0;

  auto stage = [&](int c) {
    const int buf = c & 1;
    const float* gt = trb + (size_t)c * CH * 36;
    float* lt = s_tr + buf * (CH * 36);
#pragma unroll
    for (int i = 0; i < 18; ++i) gll16(gt + i * 256 + lane * 4, lt + i * 256);
    const float* gf = ftb + (size_t)c * CH * 6;
    float* lf = s_ft + buf * (CH * 6);
#pragma unroll
    for (int i = 0; i < 3; ++i) gll16(gf + i * 256 + lane * 4, lf + i * 256);
  };

  // consumes layout0, produces layout1 (lane (g,l) -> delta_new[g])
  // minimal 8-lane-group reduce: xor1, xor2, then half-mirror (l -> 7-l).
  auto stepA = [&](float tr, float ft, int slot) {
    float s = tr + delta;                   // exact: same single add as ref
    float m = fmaxf(s, dppf<0xB1>(s));      // xor1 (quad_perm 1,0,3,2)
    m = fmaxf(m, dppf<0x4E>(m));            // xor2 (quad_perm 2,3,0,1)
    m = fmaxf(m, dppf<0x141>(m));           // xor4 via row_half_mirror
    u64 bal = __ballot(s == m);             // bits at 8i+j
    bool cap = (lane == slot);
    mlo = cap ? (u32)bal : mlo;
    mhi = cap ? (u32)(bal >> 32) : mhi;
    delta = m + ft;
  };

  // consumes layout1, produces layout0 (lane (g,l) -> delta_new[l])
  auto stepB = [&](float tr, float ft, int slot) {
    float s = tr + delta;
    float m = fmaxf(s, dppf<0x128>(s));     // xor8 (row_ror:8)
    m = pl16max(m);                         // xor16
    m = pl32max(m);                         // xor32
    u64 bal = __ballot(s == m);             // bits at 8j+i
    bool cap = (lane == slot);
    mlo = cap ? (u32)bal : mlo;
    mhi = cap ? (u32)(bal >> 32) : mhi;
    delta = m + ft;
  };

  auto flush = [&](int base) {  // lane holds ballot of step base+lane
    const u32 ub = (u32)(base >> 6) & 63;
    // A-unpack (odd step => odd lane): psi_i = ctz of (bal >> 8i) & 63
    u32 pA = (u32)__builtin_ctz((mlo & 63u) | 64u);
    pA |= (u32)__builtin_ctz(((mlo >> 8) & 63u) | 64u) << 3;
    pA |= (u32)__builtin_ctz(((mlo >> 16) & 63u) | 64u) << 6;
    pA |= (u32)__builtin_ctz(((mlo >> 24) & 63u) | 64u) << 9;
    pA |= (u32)__builtin_ctz((mhi & 63u) | 64u) << 12;
    pA |= (u32)__builtin_ctz(((mhi >> 8) & 63u) | 64u) << 15;
    // B-unpack (even step => even lane): bits for state i at 8j+i
    u64 bal = ((u64)mhi << 32) | (u64)mlo;
    u32 pB = 0;
#pragma unroll
    for (int i = 0; i < 6; ++i) {
      u64 mm = (bal >> i) & 0x0000010101010101ULL;
      u32 j = (u32)(__builtin_ctzll(mm | (1ULL << 48)) >> 3);
      pB |= j << (3 * i);
    }
    u32 p = (lane & 1) ? pA : pB;
    s_psi[base + (((u32)lane) ^ ub)] = p;   // bank-swizzled slot
  };

// group load: 8 steps' (tr, ft) into register arrays (static indices only)
#define LOAD8(trv, ftv, g8base)                                               \
  {                                                                           \
    _Pragma("unroll") for (int q = 0; q < 8; ++q) {                           \
      trv[q] = trp[((g8base) + q) * 36 + ((q & 1) ? offTA : offTB)];          \
      ftv[q] = ftp[((g8base) + q) * 6 + ((q & 1) ? offFA : offFB)];           \
    }                                                                         \
  }

#define STEPS8(trv, ftv, base)                                                \
  {                                                                           \
    _Pragma("unroll") for (int q = 0; q < 8; ++q) {                           \
      if (q & 1) stepA(trv[q], ftv[q], ((base) + q) & 63);                    \
      else       stepB(trv[q], ftv[q], ((base) + q) & 63);                    \
    }                                                                         \
  }

  stage(0);
  asm volatile("s_waitcnt vmcnt(0)" ::: "memory");
  stage(1);

  // ---- chunk 0 (t = 1..127; t=0 skipped). t odd -> stepA, t even -> stepB.
  {
    const float* trp = s_tr;
    const float* ftp = s_ft;
    float trA[8], ftA[8], trB[8], ftB[8];
    LOAD8(trA, ftA, 0);
    LOAD8(trB, ftB, 8);
    // steps 1..7 (skip t=0)
#pragma unroll
    for (int q = 1; q < 8; ++q) {
      if (q & 1) stepA(trA[q], ftA[q], q);
      else       stepB(trA[q], ftA[q], q);
    }
    LOAD8(trA, ftA, 16);
    STEPS8(trB, ftB, 8);
#pragma unroll 1
    for (int g2 = 2; g2 < 16; g2 += 2) {
      LOAD8(trB, ftB, (g2 + 1) * 8);
      STEPS8(trA, ftA, g2 * 8);
      LOAD8(trA, ftA, (g2 + 2) * 8);   // g2==14 -> in-LDS garbage, never consumed
      STEPS8(trB, ftB, (g2 + 1) * 8);
      if ((g2 & 7) == 6) flush((g2 & 8) * 8);
    }
  }

  // ---- chunks 1..31 (tbase even => t parity == q parity)
#pragma unroll 1
  for (int c = 1; c < NCHUNK; ++c) {
    asm volatile("s_waitcnt vmcnt(0)" ::: "memory");   // chunk c resident
    if (c + 1 < NCHUNK) stage(c + 1);
    const int buf = c & 1;
    const float* trp = s_tr + buf * (CH * 36);
    const float* ftp = s_ft + buf * (CH * 6);
    const int tbase = c * CH;
    float trA[8], ftA[8], trB[8], ftB[8];
    LOAD8(trA, ftA, 0);
#pragma unroll 1
    for (int g2 = 0; g2 < 16; g2 += 2) {
      LOAD8(trB, ftB, (g2 + 1) * 8);
      STEPS8(trA, ftA, tbase + g2 * 8);
      LOAD8(trA, ftA, (g2 + 2) * 8);   // g2==14 -> in-LDS garbage, never consumed
      STEPS8(trB, ftB, tbase + (g2 + 1) * 8);
      if ((g2 & 7) == 6) flush(tbase + (g2 & 8) * 8);
    }
  }

  // ---- score + last_tag. Final step t=4095 is stepA -> layout1:
  // lane (g,l) holds delta_final[g]; groups 6,7 duplicate state 5 exactly.
  float sm = delta;
  sm = fmaxf(sm, dppf<0xB1>(sm));
  sm = fmaxf(sm, dppf<0x4E>(sm));
  sm = fmaxf(sm, dppf<0x141>(sm));
  sm = fmaxf(sm, dppf<0x128>(sm));
  sm = pl16max(sm);
  sm = pl32max(sm);
  u64 bs = __ballot(delta == sm);
  int last_tag = (int)((__builtin_ctzll(bs) >> 3) & 7);  // smallest g wins ties

  __syncthreads();  // all psi visible

  // ---- per-segment backpointer-map composition (exact integer scan)
  const int u = lane;
  u32 Gm = 0u | (1u << 3) | (2u << 6) | (3u << 9) | (4u << 12) | (5u << 15);
#pragma unroll 1
  for (int k = 0; k < 64; ++k) {
    u32 p = s_psi[u * 64 + (k ^ u)];
    u32 ng = 0;
#pragma unroll
    for (int x = 0; x < 6; ++x) {
      u32 j = (p >> (3 * x)) & 7;
      u32 v = (Gm >> (3 * ((j < 6) ? j : 0))) & 7;  // clamp (defensive)
      ng |= v << (3 * x);
    }
    Gm = ng;
  }

  // ---- boundary-tag chain via readlane (uniform, register-only)
  int bcur = last_tag;
  int my_b = last_tag;  // lane 63
#pragma unroll 1
  for (int v = 63; v >= 1; --v) {
    u32 Gv = (u32)__builtin_amdgcn_readlane((int)Gm, v);
    bcur = (int)((Gv >> (3 * bcur)) & 7);
    my_b = (u == v - 1) ? bcur : my_b;
  }

  // ---- per-segment walk, emit path bytes
  {
    int tag = my_b;
    unsigned char* pb = (unsigned char*)s_path;
    pb[u * 64 + 63] = (unsigned char)tag;
#pragma unroll 1
    for (int k = 63; k >= 1; --k) {
      u32 p = s_psi[u * 64 + (k ^ u)];
      tag = (int)((p >> (3 * tag)) & 7);
      pb[u * 64 + k - 1] = (unsigned char)tag;
    }
  }
  if (lane == 0) out[b] = sm;
  __syncthreads();

  // ---- coalesced float path store
  float* outp = out + NB + (size_t)b * NT;
#pragma unroll
  for (int i = 0; i < (NT / 4) / 64; ++i) {
    u32 w = s_path[lane + i * 64];
    float4 f;
    f.x = (float)(w & 255u);
    f.y = (float)((w >> 8) & 255u);
    f.z = (float)((w >> 16) & 255u);
    f.w = (float)((w >> 24) & 255u);
    ((float4*)outp)[lane + i * 64] = f;
  }
}

extern "C" void kernel_launch(void* const* d_in, const int* in_sizes, int n_in,
                              void* d_out, int out_size, void* d_ws, size_t ws_size,
                              hipStream_t stream) {
  (void)in_sizes; (void)n_in; (void)out_size; (void)d_ws; (void)ws_size;
  const float* feats = (const float*)d_in[0];
  const float* trans = (const float*)d_in[1];
  float* out = (float*)d_out;
  hipLaunchKernelGGL(viterbi_k, dim3(NB), dim3(64), 0, stream, feats, trans, out);
}

// Round 9
// 240.100 us; speedup vs baseline: 2.9519x; 1.0087x over previous
//
#include <hip/hip_runtime.h>

#define NB 256
#define NT 4096
#define CH 128
#define NCHUNK (NT / CH)

typedef unsigned int u32;
typedef unsigned long long u64;
typedef int v2i __attribute__((ext_vector_type(2)));

typedef __attribute__((address_space(1))) const u32 gas_u32;
typedef __attribute__((address_space(3))) u32 las_u32;

__device__ __forceinline__ void gll16(const void* g, void* l) {
  __builtin_amdgcn_global_load_lds((gas_u32*)g, (las_u32*)l, 16, 0, 0);
}

template <int CTRL>
__device__ __forceinline__ float dppf(float x) {
  return __int_as_float(__builtin_amdgcn_update_dpp(
      0, __float_as_int(x), CTRL, 0xF, 0xF, true));
}

// max with lane^16 partner (cross-row), VALU-speed on gfx950
__device__ __forceinline__ float pl16max(float x) {
#if __has_builtin(__builtin_amdgcn_permlane16_swap)
  v2i r = __builtin_amdgcn_permlane16_swap(__float_as_int(x), __float_as_int(x),
                                           false, false);
  return fmaxf(__int_as_float(r[0]), __int_as_float(r[1]));
#else
  return fmaxf(x, __shfl_xor(x, 16, 64));
#endif
}

// max with lane^32 partner
__device__ __forceinline__ float pl32max(float x) {
#if __has_builtin(__builtin_amdgcn_permlane32_swap)
  v2i r = __builtin_amdgcn_permlane32_swap(__float_as_int(x), __float_as_int(x),
                                           false, false);
  return fmaxf(__int_as_float(r[0]), __int_as_float(r[1]));
#else
  return fmaxf(x, __shfl_xor(x, 32, 64));
#endif
}

__global__ void __launch_bounds__(64, 1)
viterbi_k(const float* __restrict__ feats, const float* __restrict__ trans,
          float* __restrict__ out) {
  // LDS: 36864 + 6144 + 16384 + 4096 = 63488 B (< 64KB)
  __shared__ __align__(16) float s_tr[2 * CH * 36];
  __shared__ __align__(16) float s_ft[2 * CH * 6];
  __shared__ u32 s_psi[NT];
  __shared__ u32 s_path[NT / 4];

  const int b = blockIdx.x;
  const int lane = (int)threadIdx.x;
  const int g = lane >> 3;        // group index
  const int l = lane & 7;         // in-group index
  const int gg = (g < 6) ? g : 5; // clamped -> duplicate-of-5 invariant
  const int jj = (l < 6) ? l : 5;
  // A-step (odd t): roles i=g, j=l; B-step (even t): roles i=l, j=g
  const int offTA = gg * 6 + jj;   // trans[t][i=g][j=l]
  const int offTB = jj * 6 + gg;   // trans[t][i=l][j=g]
  const int offFA = gg;            // feat[t][i=g]
  const int offFB = jj;            // feat[t][i=l]

  const float* trb = trans + (size_t)b * NT * 36;
  const float* ftb = feats + (size_t)b * NT * 6;

  // layout0: lane (g,l) holds delta[jj] — lanes l>=6 duplicate state 5.
  float delta = (l == 4) ? 0.0f : -10000.0f;
  u32 mlo = 0, mhi = 0;

  auto stage = [&](int c) {
    const int buf = c & 1;
    const float* gt = trb + (size_t)c * CH * 36;
    float* lt = s_tr + buf * (CH * 36);
#pragma unroll
    for (int i = 0; i < 18; ++i) gll16(gt + i * 256 + lane * 4, lt + i * 256);
    const float* gf = ftb + (size_t)c * CH * 6;
    float* lf = s_ft + buf * (CH * 6);
#pragma unroll
    for (int i = 0; i < 3; ++i) gll16(gf + i * 256 + lane * 4, lf + i * 256);
  };

  // consumes layout0, produces layout1 (lane (g,l) -> delta_new[g])
  auto stepA = [&](float tr, float ft, int slot) {
    float s = tr + delta;                   // exact: same single add as ref
    float m = fmaxf(s, dppf<0xB1>(s));      // xor1 (quad_perm 1,0,3,2)
    m = fmaxf(m, dppf<0x4E>(m));            // xor2 (quad_perm 2,3,0,1)
    m = fmaxf(m, dppf<0x141>(m));           // xor4 via row_half_mirror
    u64 bal = __ballot(s == m);             // bits at 8i+j
    bool cap = (lane == slot);
    mlo = cap ? (u32)bal : mlo;
    mhi = cap ? (u32)(bal >> 32) : mhi;
    delta = m + ft;
  };

  // consumes layout1, produces layout0 (lane (g,l) -> delta_new[l])
  auto stepB = [&](float tr, float ft, int slot) {
    float s = tr + delta;
    float m = fmaxf(s, dppf<0x128>(s));     // xor8 (row_ror:8)
    m = pl16max(m);                         // xor16
    m = pl32max(m);                         // xor32
    u64 bal = __ballot(s == m);             // bits at 8j+i
    bool cap = (lane == slot);
    mlo = cap ? (u32)bal : mlo;
    mhi = cap ? (u32)(bal >> 32) : mhi;
    delta = m + ft;
  };

  auto flush = [&](int base) {  // lane holds ballot of step base+lane
    const u32 ub = (u32)(base >> 6) & 63;
    // A-unpack (odd step => odd lane): psi_i = ctz of (bal >> 8i) & 63
    u32 pA = (u32)__builtin_ctz((mlo & 63u) | 64u);
    pA |= (u32)__builtin_ctz(((mlo >> 8) & 63u) | 64u) << 3;
    pA |= (u32)__builtin_ctz(((mlo >> 16) & 63u) | 64u) << 6;
    pA |= (u32)__builtin_ctz(((mlo >> 24) & 63u) | 64u) << 9;
    pA |= (u32)__builtin_ctz((mhi & 63u) | 64u) << 12;
    pA |= (u32)__builtin_ctz(((mhi >> 8) & 63u) | 64u) << 15;
    // B-unpack (even step => even lane): bits for state i at 8j+i
    u64 bal = ((u64)mhi << 32) | (u64)mlo;
    u32 pB = 0;
#pragma unroll
    for (int i = 0; i < 6; ++i) {
      u64 mm = (bal >> i) & 0x0000010101010101ULL;
      u32 j = (u32)(__builtin_ctzll(mm | (1ULL << 48)) >> 3);
      pB |= j << (3 * i);
    }
    u32 p = (lane & 1) ? pA : pB;
    s_psi[base + (((u32)lane) ^ ub)] = p;   // bank-swizzled slot
  };

// burst load of one 8-step group (chunk prologue only)
#define LOAD8(trv, ftv, g8base)                                               \
  {                                                                           \
    _Pragma("unroll") for (int q = 0; q < 8; ++q) {                           \
      trv[q] = trp[((g8base) + q) * 36 + ((q & 1) ? offTA : offTB)];          \
      ftv[q] = ftp[((g8base) + q) * 6 + ((q & 1) ? offFA : offFB)];           \
    }                                                                         \
  }

// 8 steps with the NEXT group's loads interleaved 2-per-step: at any consume
// point, outstanding LDS ops <= 14 (lgkmcnt-encodable, no false waits).
#define STEPS8L(trv, ftv, base, ntr, nft, ng8)                                \
  {                                                                           \
    _Pragma("unroll") for (int q = 0; q < 8; ++q) {                           \
      if (q & 1) stepA(trv[q], ftv[q], ((base) + q) & 63);                    \
      else       stepB(trv[q], ftv[q], ((base) + q) & 63);                    \
      ntr[q] = trp[((ng8) + q) * 36 + ((q & 1) ? offTA : offTB)];             \
      nft[q] = ftp[((ng8) + q) * 6 + ((q & 1) ? offFA : offFB)];              \
    }                                                                         \
  }

// 8 steps, no loads (last group of each chunk)
#define STEPS8(trv, ftv, base)                                                \
  {                                                                           \
    _Pragma("unroll") for (int q = 0; q < 8; ++q) {                           \
      if (q & 1) stepA(trv[q], ftv[q], ((base) + q) & 63);                    \
      else       stepB(trv[q], ftv[q], ((base) + q) & 63);                    \
    }                                                                         \
  }

  stage(0);
  asm volatile("s_waitcnt vmcnt(0)" ::: "memory");
  stage(1);

  // ---- chunk 0 (t = 1..127; t=0 skipped). t odd -> stepA, t even -> stepB.
  {
    const float* trp = s_tr;
    const float* ftp = s_ft;
    float trA[8], ftA[8], trB[8], ftB[8];
    LOAD8(trA, ftA, 0);
    LOAD8(trB, ftB, 8);
    // steps 1..7 (skip t=0)
#pragma unroll
    for (int q = 1; q < 8; ++q) {
      if (q & 1) stepA(trA[q], ftA[q], q);
      else       stepB(trA[q], ftA[q], q);
    }
    STEPS8L(trB, ftB, 8, trA, ftA, 16);
#pragma unroll 1
    for (int g2 = 2; g2 < 14; g2 += 2) {
      STEPS8L(trA, ftA, g2 * 8, trB, ftB, (g2 + 1) * 8);
      STEPS8L(trB, ftB, (g2 + 1) * 8, trA, ftA, (g2 + 2) * 8);
      if ((g2 & 7) == 6) flush((g2 & 8) * 8);   // g2=6 -> flush(0)
    }
    // peeled groups 14,15
    STEPS8L(trA, ftA, 112, trB, ftB, 120);
    STEPS8(trB, ftB, 120);
    flush(64);
  }

  // ---- chunks 1..31 (tbase even => t parity == q parity)
#pragma unroll 1
  for (int c = 1; c < NCHUNK; ++c) {
    asm volatile("s_waitcnt vmcnt(0)" ::: "memory");   // chunk c resident
    if (c + 1 < NCHUNK) stage(c + 1);
    const int buf = c & 1;
    const float* trp = s_tr + buf * (CH * 36);
    const float* ftp = s_ft + buf * (CH * 6);
    const int tbase = c * CH;
    float trA[8], ftA[8], trB[8], ftB[8];
    LOAD8(trA, ftA, 0);
#pragma unroll 1
    for (int g2 = 0; g2 < 14; g2 += 2) {
      STEPS8L(trA, ftA, tbase + g2 * 8, trB, ftB, (g2 + 1) * 8);
      STEPS8L(trB, ftB, tbase + (g2 + 1) * 8, trA, ftA, (g2 + 2) * 8);
      if ((g2 & 7) == 6) flush(tbase + (g2 & 8) * 8);  // g2=6 -> flush(tbase)
    }
    // peeled groups 14,15
    STEPS8L(trA, ftA, tbase + 112, trB, ftB, 120);
    STEPS8(trB, ftB, tbase + 120);
    flush(tbase + 64);
  }

  // ---- score + last_tag. Final step t=4095 is stepA -> layout1:
  // lane (g,l) holds delta_final[g]; groups 6,7 duplicate state 5 exactly.
  float sm = delta;
  sm = fmaxf(sm, dppf<0xB1>(sm));
  sm = fmaxf(sm, dppf<0x4E>(sm));
  sm = fmaxf(sm, dppf<0x141>(sm));
  sm = fmaxf(sm, dppf<0x128>(sm));
  sm = pl16max(sm);
  sm = pl32max(sm);
  u64 bs = __ballot(delta == sm);
  int last_tag = (int)((__builtin_ctzll(bs) >> 3) & 7);  // smallest g wins ties

  __syncthreads();  // all psi visible

  // ---- per-segment backpointer-map composition (exact integer scan)
  const int u = lane;
  u32 Gm = 0u | (1u << 3) | (2u << 6) | (3u << 9) | (4u << 12) | (5u << 15);
#pragma unroll 1
  for (int k = 0; k < 64; ++k) {
    u32 p = s_psi[u * 64 + (k ^ u)];
    u32 ng = 0;
#pragma unroll
    for (int x = 0; x < 6; ++x) {
      u32 j = (p >> (3 * x)) & 7;
      u32 v = (Gm >> (3 * ((j < 6) ? j : 0))) & 7;  // clamp (defensive)
      ng |= v << (3 * x);
    }
    Gm = ng;
  }

  // ---- boundary-tag chain via readlane (uniform, register-only)
  int bcur = last_tag;
  int my_b = last_tag;  // lane 63
#pragma unroll 1
  for (int v = 63; v >= 1; --v) {
    u32 Gv = (u32)__builtin_amdgcn_readlane((int)Gm, v);
    bcur = (int)((Gv >> (3 * bcur)) & 7);
    my_b = (u == v - 1) ? bcur : my_b;
  }

  // ---- per-segment walk, emit path bytes
  {
    int tag = my_b;
    unsigned char* pb = (unsigned char*)s_path;
    pb[u * 64 + 63] = (unsigned char)tag;
#pragma unroll 1
    for (int k = 63; k >= 1; --k) {
      u32 p = s_psi[u * 64 + (k ^ u)];
      tag = (int)((p >> (3 * tag)) & 7);
      pb[u * 64 + k - 1] = (unsigned char)tag;
    }
  }
  if (lane == 0) out[b] = sm;
  __syncthreads();

  // ---- coalesced float path store
  float* outp = out + NB + (size_t)b * NT;
#pragma unroll
  for (int i = 0; i < (NT / 4) / 64; ++i) {
    u32 w = s_path[lane + i * 64];
    float4 f;
    f.x = (float)(w & 255u);
    f.y = (float)((w >> 8) & 255u);
    f.z = (float)((w >> 16) & 255u);
    f.w = (float)((w >> 24) & 255u);
    ((float4*)outp)[lane + i * 64] = f;
  }
}

extern "C" void kernel_launch(void* const* d_in, const int* in_sizes, int n_in,
                              void* d_out, int out_size, void* d_ws, size_t ws_size,
                              hipStream_t stream) {
  (void)in_sizes; (void)n_in; (void)out_size; (void)d_ws; (void)ws_size;
  const float* feats = (const float*)d_in[0];
  const float* trans = (const float*)d_in[1];
  float* out = (float*)d_out;
  hipLaunchKernelGGL(viterbi_k, dim3(NB), dim3(64), 0, stream, feats, trans, out);
}